// Round 1
// baseline (92.949 us; speedup 1.0000x reference)
//
#include <hip/hip_runtime.h>
#include <math.h>

#define N_RAYS 262144
#define N_SPHERES 256

__global__ __launch_bounds__(256) void ray_sphere_kernel(
    const float* __restrict__ ro,   // (N,3)
    const float* __restrict__ rd,   // (N,3)
    const float* __restrict__ sc,   // (M,3)
    const float* __restrict__ sr,   // (M,)
    float* __restrict__ out)        // 8N floats: t_hit | idx | hit_points | hit_normals
{
    __shared__ float4 sph[N_SPHERES];  // x,y,z = center, w = |c|^2 - r^2

    const int tid = threadIdx.x;
    {
        const float cx = sc[3 * tid + 0];
        const float cy = sc[3 * tid + 1];
        const float cz = sc[3 * tid + 2];
        const float r  = sr[tid];
        sph[tid] = make_float4(cx, cy, cz,
                               fmaf(cz, cz, fmaf(cy, cy, cx * cx)) - r * r);
    }
    __syncthreads();

    const int i = blockIdx.x * blockDim.x + tid;

    const float ox = ro[3 * i + 0], oy = ro[3 * i + 1], oz = ro[3 * i + 2];
    const float dx = rd[3 * i + 0], dy = rd[3 * i + 1], dz = rd[3 * i + 2];

    const float a       = fmaf(dz, dz, fmaf(dy, dy, dx * dx));
    const float d_dot_o = fmaf(dz, oz, fmaf(dy, oy, dx * ox));
    const float o_norm2 = fmaf(oz, oz, fmaf(oy, oy, ox * ox));
    const float inva    = 1.0f / a;
    const float nd      = -d_dot_o;     // fold into m's fma chain
    const float px = -2.0f * ox, py = -2.0f * oy, pz = -2.0f * oz;

    // Track the min in u-space: u = a*t = -hb -/+ sqrt(disc/4). a>0 so the
    // argmin and all sign tests are identical to t-space (monotone scaling);
    // one multiply by inva at the end recovers t.
    //
    // BRANCH-FREE inner loop: the previous per-sphere __ballot skip put a
    // v_cmp -> s_cbranch in every unrolled iteration, which (a) blocked the
    // compiler from batching ds_read_b128s across iterations and (b) forced a
    // per-iteration lgkmcnt(0)-style serialization. With only 4 waves/SIMD of
    // TLP (grid-capped), that latency went unhidden (~200 cyc/iter observed vs
    // ~20 cyc of VALU work). Straight-line code lets the compiler hoist the 8
    // ds_reads per unrolled block and pipeline with fine-grained lgkmcnt(N).
    // Lanes with disc<0 get sq=NaN -> u=NaN -> all compares false -> no update.
    float best_u = INFINITY;
    int   best_j = 0;  // argmin of all-inf row is 0 (matches jnp.argmin)

    #pragma unroll 8
    for (int j = 0; j < N_SPHERES; ++j) {
        const float4 s = sph[j];
        const float m    = fmaf(dz, s.z, fmaf(dy, s.y, fmaf(dx, s.x, nd)));      // -b/2
        const float c    = fmaf(pz, s.z, fmaf(py, s.y, fmaf(px, s.x, o_norm2 + s.w)));
        const float disc = fmaf(m, m, -(a * c));                                  // disc/4
        const float sq = __builtin_amdgcn_sqrtf(disc);   // raw v_sqrt_f32; NaN if disc<0
        const float u1 = m - sq;
        const float u2 = m + sq;
        const float u  = (u1 > 0.0f) ? u1 : u2;          // min positive root (u2 >= u1)
        // valid <=> u > 0; strict < keeps first-min tie-break like jnp.argmin
        const bool better = (u > 0.0f) & (u < best_u);
        best_u = better ? u : best_u;
        best_j = better ? j : best_j;
    }

    const float best_t = best_u * inva;
    const bool any_hit = isfinite(best_t);

    const float hx = fmaf(best_t, dx, ox);
    const float hy = fmaf(best_t, dy, oy);
    const float hz = fmaf(best_t, dz, oz);

    const float4 cs = sph[any_hit ? best_j : 0];
    float nx = hx - cs.x, ny = hy - cs.y, nz = hz - cs.z;
    const float inv_nrm = __builtin_amdgcn_rsqf(fmaf(nz, nz, fmaf(ny, ny, nx * nx)));
    nx *= inv_nrm; ny *= inv_nrm; nz *= inv_nrm;
    if (!any_hit) { nx = 0.0f; ny = 0.0f; nz = 0.0f; }

    // outputs: t_hit [0,N) | sphere_idx [N,2N) | hit_points [2N,5N) | normals [5N,8N)
    out[i]            = best_t;
    out[N_RAYS + i]   = any_hit ? (float)best_j : -1.0f;
    float* hp = out + 2 * N_RAYS;
    hp[3 * i + 0] = hx; hp[3 * i + 1] = hy; hp[3 * i + 2] = hz;
    float* hn = out + 5 * N_RAYS;
    hn[3 * i + 0] = nx; hn[3 * i + 1] = ny; hn[3 * i + 2] = nz;
}

extern "C" void kernel_launch(void* const* d_in, const int* in_sizes, int n_in,
                              void* d_out, int out_size, void* d_ws, size_t ws_size,
                              hipStream_t stream) {
    const float* ro = (const float*)d_in[0];
    const float* rd = (const float*)d_in[1];
    const float* sc = (const float*)d_in[2];
    const float* sr = (const float*)d_in[3];
    float* out = (float*)d_out;

    dim3 block(256);
    dim3 grid(N_RAYS / 256);
    ray_sphere_kernel<<<grid, block, 0, stream>>>(ro, rd, sc, sr, out);
}

// Round 2
// 86.613 us; speedup vs baseline: 1.0732x; 1.0732x over previous
//
#include <hip/hip_runtime.h>
#include <math.h>

#define N_RAYS 262144
#define N_SPHERES 256

// Two-wide f32 vector: contracts to v_pk_fma_f32 / v_pk_mul_f32 (VOP3P) on
// gfx950, processing 2 spheres per instruction. Elementwise numerics are
// identical to the scalar fmaf chain (same IEEE fma, same order).
typedef float f2 __attribute__((ext_vector_type(2)));

__global__ __launch_bounds__(256) void ray_sphere_kernel(
    const float* __restrict__ ro,   // (N,3)
    const float* __restrict__ rd,   // (N,3)
    const float* __restrict__ sc,   // (M,3)
    const float* __restrict__ sr,   // (M,)
    float* __restrict__ out)        // 8N floats: t_hit | idx | hit_points | hit_normals
{
    // SoA so sphere PAIRS load as one ds_read_b64 per component and feed
    // packed math. All lanes read the same address -> LDS broadcast, no
    // bank conflicts.
    __shared__ __align__(16) float sx[N_SPHERES];
    __shared__ __align__(16) float sy[N_SPHERES];
    __shared__ __align__(16) float sz[N_SPHERES];
    __shared__ __align__(16) float sw[N_SPHERES];  // |c|^2 - r^2

    const int tid = threadIdx.x;
    {
        const float cx = sc[3 * tid + 0];
        const float cy = sc[3 * tid + 1];
        const float cz = sc[3 * tid + 2];
        const float r  = sr[tid];
        sx[tid] = cx; sy[tid] = cy; sz[tid] = cz;
        sw[tid] = fmaf(cz, cz, fmaf(cy, cy, cx * cx)) - r * r;
    }
    __syncthreads();

    const int i = blockIdx.x * blockDim.x + tid;

    const float ox = ro[3 * i + 0], oy = ro[3 * i + 1], oz = ro[3 * i + 2];
    const float dx = rd[3 * i + 0], dy = rd[3 * i + 1], dz = rd[3 * i + 2];

    const float a       = fmaf(dz, dz, fmaf(dy, dy, dx * dx));
    const float d_dot_o = fmaf(dz, oz, fmaf(dy, oy, dx * ox));
    const float o_norm2 = fmaf(oz, oz, fmaf(oy, oy, ox * ox));
    const float inva    = 1.0f / a;
    const float nd      = -d_dot_o;     // fold into m's fma chain
    const float px = -2.0f * ox, py = -2.0f * oy, pz = -2.0f * oz;

    // Min tracked in u-space: u = a*t (a>0, monotone) -> one inva mul at end.
    // NOTE (journal): measured dur_us is ~82 us of harness poison fills
    // (2 x 268 MB fillBuffer @ ~41 us, see rocprof top-5) + the kernel.
    // Ballot-skip kernel share ~4 us; branch-free (r1) was ~11 us. The
    // skip path (m, c, disc + ballot per sphere) is the dominant kernel
    // cost -> pack 2 spheres per instruction with pk f32 math, one ballot
    // per pair. Hit path (rare, ~6%/sphere per r0 measurement) stays
    // scalar, processed in j order to preserve the first-min tie-break.
    float best_u = INFINITY;
    int   best_j = 0;  // argmin of all-inf row is 0 (matches jnp.argmin)

    #pragma unroll 4
    for (int j = 0; j < N_SPHERES; j += 2) {
        const f2 sx2 = *(const f2*)&sx[j];
        const f2 sy2 = *(const f2*)&sy[j];
        const f2 sz2 = *(const f2*)&sz[j];
        const f2 sw2 = *(const f2*)&sw[j];
        // m = -b/2 ; c = |o-c|^2 - r^2 ; disc = disc/4
        const f2 m2 = sz2 * dz + (sy2 * dy + (sx2 * dx + nd));
        const f2 c2 = sz2 * pz + (sy2 * py + (sx2 * px + (sw2 + o_norm2)));
        const f2 disc2 = m2 * m2 - a * c2;
        // Wave-uniform skip over the PAIR: any lane hitting either sphere.
        if (__ballot(fmaxf(disc2.x, disc2.y) >= 0.0f) != 0ull) {
            // Lanes/spheres with disc<0 get sq=NaN -> u=NaN -> compares
            // false -> no update. No per-lane mask needed.
            {
                const float sq = __builtin_amdgcn_sqrtf(disc2.x);
                const float u1 = m2.x - sq;
                const float u2 = m2.x + sq;
                const float u  = (u1 > 0.0f) ? u1 : u2;
                if (u > 0.0f && u < best_u) { best_u = u; best_j = j; }
            }
            {
                const float sq = __builtin_amdgcn_sqrtf(disc2.y);
                const float u1 = m2.y - sq;
                const float u2 = m2.y + sq;
                const float u  = (u1 > 0.0f) ? u1 : u2;
                if (u > 0.0f && u < best_u) { best_u = u; best_j = j + 1; }
            }
        }
    }

    const float best_t = best_u * inva;
    const bool any_hit = isfinite(best_t);

    const float hx = fmaf(best_t, dx, ox);
    const float hy = fmaf(best_t, dy, oy);
    const float hz = fmaf(best_t, dz, oz);

    const int jj = any_hit ? best_j : 0;
    float nx = hx - sx[jj], ny = hy - sy[jj], nz = hz - sz[jj];
    const float inv_nrm = __builtin_amdgcn_rsqf(fmaf(nz, nz, fmaf(ny, ny, nx * nx)));
    nx *= inv_nrm; ny *= inv_nrm; nz *= inv_nrm;
    if (!any_hit) { nx = 0.0f; ny = 0.0f; nz = 0.0f; }

    // outputs: t_hit [0,N) | sphere_idx [N,2N) | hit_points [2N,5N) | normals [5N,8N)
    out[i]            = best_t;
    out[N_RAYS + i]   = any_hit ? (float)best_j : -1.0f;
    float* hp = out + 2 * N_RAYS;
    hp[3 * i + 0] = hx; hp[3 * i + 1] = hy; hp[3 * i + 2] = hz;
    float* hn = out + 5 * N_RAYS;
    hn[3 * i + 0] = nx; hn[3 * i + 1] = ny; hn[3 * i + 2] = nz;
}

extern "C" void kernel_launch(void* const* d_in, const int* in_sizes, int n_in,
                              void* d_out, int out_size, void* d_ws, size_t ws_size,
                              hipStream_t stream) {
    const float* ro = (const float*)d_in[0];
    const float* rd = (const float*)d_in[1];
    const float* sc = (const float*)d_in[2];
    const float* sr = (const float*)d_in[3];
    float* out = (float*)d_out;

    dim3 block(256);
    dim3 grid(N_RAYS / 256);
    ray_sphere_kernel<<<grid, block, 0, stream>>>(ro, rd, sc, sr, out);
}